// Round 6
// baseline (296.939 us; speedup 1.0000x reference)
//
#include <hip/hip_runtime.h>

// ud_MultiheadSoftmaxAttention: B=2 T=2048 D=1024 H=16 hd=64
// Pipeline: prep(fp32->bf16 + row scales) -> batched QKV GEMM (bf16 MFMA,
//           dbuf+counted vmcnt; V written directly transposed) -> flash
//           attention (LDS-staged K/V, swapped-operand in-register softmax,
//           P redistributed via ds_bpermute, b128 conflict-free V reads)
//           -> output GEMM.
// Per-query additive score biases (logvar/w_phi terms) cancel in softmax;
// only the per-row temperature 1/(8*max(mean(phi),1e-6)) survives.

typedef __bf16 bf16x8 __attribute__((ext_vector_type(8)));
typedef __bf16 bf16x2 __attribute__((ext_vector_type(2)));
typedef float f32x4 __attribute__((ext_vector_type(4)));
typedef unsigned short u16;
typedef unsigned int u32;
typedef u16 u16x8 __attribute__((ext_vector_type(8)));
typedef u32 u32x4 __attribute__((ext_vector_type(4)));

#define GLD_TO_LDS(g, l) __builtin_amdgcn_global_load_lds( \
    (const __attribute__((address_space(1))) void*)(g),    \
    (__attribute__((address_space(3))) void*)(l), 16, 0, 0)

__device__ __forceinline__ u16 f2b(float f) {
  u32 u = __builtin_bit_cast(u32, f);
  u += 0x7fffu + ((u >> 16) & 1u);   // RNE
  return (u16)(u >> 16);
}

// ---------------- prep: fp32 -> bf16 conversions + softmax row scales ----
__global__ __launch_bounds__(256) void prep_kernel(
    const float* __restrict__ query, const float* __restrict__ key,
    const float* __restrict__ value, const float* __restrict__ Wq,
    const float* __restrict__ Wk, const float* __restrict__ Wv,
    const float* __restrict__ Wo, const float* __restrict__ phi,
    u16* __restrict__ Xq, u16* __restrict__ Xk, u16* __restrict__ Xv,
    u16* __restrict__ Wqb, u16* __restrict__ Wkb, u16* __restrict__ Wvb,
    u16* __restrict__ Wob, float* __restrict__ rscale)
{
  const long gid = (long)blockIdx.x * 256 + threadIdx.x;  // 0..4M-1
  const long e = gid * 4;
  const float* src; u16* dst; long off;
  if (e < 4194304L)       { src = query; dst = Xq;  off = e; }
  else if (e < 8388608L)  { src = key;   dst = Xk;  off = e - 4194304L; }
  else if (e < 12582912L) { src = value; dst = Xv;  off = e - 8388608L; }
  else if (e < 13631488L) { src = Wq;    dst = Wqb; off = e - 12582912L; }
  else if (e < 14680064L) { src = Wk;    dst = Wkb; off = e - 13631488L; }
  else if (e < 15728640L) { src = Wv;    dst = Wvb; off = e - 14680064L; }
  else                    { src = Wo;    dst = Wob; off = e - 15728640L; }
  const float4 v = *(const float4*)(src + off);
  ushort4 o;
  o.x = f2b(v.x); o.y = f2b(v.y); o.z = f2b(v.z); o.w = f2b(v.w);
  *(ushort4*)(dst + off) = o;

  if (gid < 4096) {  // per-token softmax temperature (log2e folded in)
    const float4 p0 = *(const float4*)(phi + gid * 8);
    const float4 p1 = *(const float4*)(phi + gid * 8 + 4);
    const float mean = (p0.x + p0.y + p0.z + p0.w + p1.x + p1.y + p1.z + p1.w) * 0.125f;
    rscale[gid] = 1.4426950408889634f / (8.0f * fmaxf(mean, 1e-6f));
  }
}

// ---------------- GEMM: C[m][n] = A[m][:] . Bw[n][:] + bias[n] -----------
// 128x128 tile, BK=32, 256 thr (4 waves 2x2), global_load_lds width-16,
// double-buffered LDS + counted vmcnt(4) + raw barriers (no full drain).
// MODE 0: bf16 out [b][h][t][64]; MODE 1: f32 flat; MODE 2: bf16 V^T
// [b][h][d][t] (scattered 2B stores merge to full lines in L2).
template<int MODE>
__device__ __forceinline__ void gemm_body(
    u16 (*As)[4096], u16 (*Bs)[4096], int m0, int n0,
    const u16* __restrict__ A, const u16* __restrict__ Bw,
    const float* __restrict__ bias, void* __restrict__ Cout)
{
  constexpr int K = 1024;
  const int t = threadIdx.x;
  const int lane = t & 63, w = t >> 6;
  const int g = lane >> 4, c = lane & 15;
  const int srow = t >> 2, skc = (t & 3) * 8;
  const u16* gA = A + (size_t)(m0 + srow) * K + skc;
  const u16* gB = Bw + (size_t)(n0 + srow) * K + skc;
  const int wm = (w >> 1) * 64, wn = (w & 1) * 64;

  f32x4 acc[4][4] = {};

#define STG(b_, k0_) do {                              \
    GLD_TO_LDS(gA + (k0_), &As[b_][w * 512]);          \
    GLD_TO_LDS(gA + 64 * K + (k0_), &As[b_][w * 512 + 2048]); \
    GLD_TO_LDS(gB + (k0_), &Bs[b_][w * 512]);          \
    GLD_TO_LDS(gB + 64 * K + (k0_), &Bs[b_][w * 512 + 2048]); \
  } while (0)

  STG(0, 0);
  for (int i = 0; i < 32; ++i) {
    const int buf = i & 1;
    if (i < 31) {
      STG(buf ^ 1, (i + 1) * 32);
      asm volatile("s_waitcnt vmcnt(4)" ::: "memory");  // current tile drained
    } else {
      asm volatile("s_waitcnt vmcnt(0)" ::: "memory");
    }
    __builtin_amdgcn_s_barrier();
    bf16x8 af[4], bfr[4];
#pragma unroll
    for (int mi = 0; mi < 4; ++mi)
      af[mi] = *(const bf16x8*)(&As[buf][0] + (wm + mi * 16 + c) * 32 + g * 8);
#pragma unroll
    for (int ni = 0; ni < 4; ++ni)
      bfr[ni] = *(const bf16x8*)(&Bs[buf][0] + (wn + ni * 16 + c) * 32 + g * 8);
    __builtin_amdgcn_s_setprio(1);
#pragma unroll
    for (int mi = 0; mi < 4; ++mi)
#pragma unroll
      for (int ni = 0; ni < 4; ++ni)
        acc[mi][ni] = __builtin_amdgcn_mfma_f32_16x16x32_bf16(
            af[mi], bfr[ni], acc[mi][ni], 0, 0, 0);
    __builtin_amdgcn_s_setprio(0);
    __builtin_amdgcn_s_barrier();  // reads done before next overwrite
  }
#undef STG

#pragma unroll
  for (int ni = 0; ni < 4; ++ni) {
    const int ncol = n0 + wn + ni * 16 + c;
    const float bv = bias[ncol];
#pragma unroll
    for (int mi = 0; mi < 4; ++mi) {
#pragma unroll
      for (int r = 0; r < 4; ++r) {
        const int mrow = m0 + wm + mi * 16 + g * 4 + r;  // C/D: col=lane&15, row=(lane>>4)*4+r
        const float val = acc[mi][ni][r] + bv;
        if (MODE == 0) {
          const int bb = mrow >> 11, tt = mrow & 2047;
          const int hh = ncol >> 6, dd = ncol & 63;
          ((u16*)Cout)[((((size_t)bb * 16 + hh) * 2048 + tt) << 6) + dd] = f2b(val);
        } else if (MODE == 2) {
          const int bb = mrow >> 11, tt = mrow & 2047;
          const int hh = ncol >> 6, dd = ncol & 63;
          ((u16*)Cout)[((((size_t)bb * 16 + hh) * 64 + dd) << 11) + tt] = f2b(val);
        } else {
          ((float*)Cout)[(size_t)mrow * 1024 + ncol] = val;
        }
      }
    }
  }
}

__global__ __launch_bounds__(256) void gemm_qkv_kernel(
    const u16* __restrict__ Xq, const u16* __restrict__ Xk, const u16* __restrict__ Xv,
    const u16* __restrict__ Wqb, const u16* __restrict__ Wkb, const u16* __restrict__ Wvb,
    const float* __restrict__ bq, const float* __restrict__ bk, const float* __restrict__ bv,
    u16* __restrict__ Qh, u16* __restrict__ Kh, u16* __restrict__ Vt)
{
  __shared__ __align__(16) u16 As[2][4096], Bs[2][4096];
  // bijective chunked XCD remap: 768 blocks = 8 chunks x 96 -> x-siblings
  // (sharing a 256KB A-panel) stay on one XCD's L2.
  const u32 n = blockIdx.z * 256u + blockIdx.y * 8u + blockIdx.x;
  const u32 nl = (n & 7u) * 96u + (n >> 3);
  const int bx = nl & 7, by = (nl >> 3) & 31, bz = nl >> 8;
  if (bz == 2) {
    gemm_body<2>(As, Bs, by * 128, bx * 128, Xv, Wvb, bv, Vt);
  } else if (bz == 1) {
    gemm_body<0>(As, Bs, by * 128, bx * 128, Xk, Wkb, bk, Kh);
  } else {
    gemm_body<0>(As, Bs, by * 128, bx * 128, Xq, Wqb, bq, Qh);
  }
}

__global__ __launch_bounds__(256) void gemm_o_kernel(
    const u16* __restrict__ Oh, const u16* __restrict__ Wob,
    const float* __restrict__ bo, float* __restrict__ out)
{
  __shared__ __align__(16) u16 As[2][4096], Bs[2][4096];
  const u32 n = blockIdx.y * 8u + blockIdx.x;
  const u32 nl = (n & 7u) * 32u + (n >> 3);
  gemm_body<1>(As, Bs, (int)(nl >> 3) * 128, (int)(nl & 7) * 128, Oh, Wob, bo, out);
}

// ---------------- flash attention ----------------------------------------
// grid 1024 blocks (XCD-swizzled), 256 thr = 4 waves, 16 q-rows each, KB=64.
// K/V staged in LDS (dbuf, counted vmcnt(4)). Swapped QK^T: S^T = mfma(K,Q),
// lane owns query col c -> softmax fully in-register (defer-max THR=8,
// lane-local l). P redistributed across g-groups via 16 ds_bpermute + 8
// cndmask so PV B-frag keys (32kk+8g+jj) are lane-resident; V^T read as
// b128 (conflict-free pattern, 0 bank conflicts measured in round 4).
__global__ __launch_bounds__(256) void attn_kernel(
    const u16* __restrict__ Qh, const u16* __restrict__ Kh,
    const u16* __restrict__ Vt, const float* __restrict__ rscale,
    u16* __restrict__ Oh)
{
  __shared__ __align__(16) u16 Ks[2][4096];  // [buf][64 keys][64 d], swizzled
  __shared__ __align__(16) u16 Vs[2][4096];  // [buf][64 d][64 keys], swizzled

  // bijective XCD remap: group consecutive bh per XCD so K/V stay L2-resident
  const u32 orig = blockIdx.y * 32 + blockIdx.x;   // HW dispatch-linear id
  const u32 newL = (orig & 7u) * 128u + (orig >> 3);
  const int qx = newL & 31, bh = newL >> 5;
  const int b = bh >> 4, h = bh & 15;

  const int t = threadIdx.x;
  const int w = t >> 6, lane = t & 63;
  const int g = lane >> 4, c = lane & 15;
  const int q0 = qx * 64 + w * 16;
  const int swz = (c & 7) << 4;          // read-side XOR swizzle (byte units)

  const u16* Qb = Qh + (size_t)bh * (2048 * 64);
  const u16* Kb = Kh + (size_t)bh * (2048 * 64);
  const u16* Vb = Vt + (size_t)bh * (64 * 2048);

  // staging geometry: 256 thr x 16B = 4KB/instr = 32 rows x 128B
  const int sr = t >> 3;                       // row 0..31
  const int sx = ((t & 7) ^ (sr & 7)) * 8;     // inverse-swizzled u16 col

  // Q fragment (B-operand: col=q=c, k=d) with per-row temperature folded in
  const float rs = rscale[b * 2048 + q0 + c];
  bf16x8 qf0, qf1;
  {
    const u16x8 a0 = *(const u16x8*)(Qb + (size_t)(q0 + c) * 64 + g * 8);
    const u16x8 a1 = *(const u16x8*)(Qb + (size_t)(q0 + c) * 64 + 32 + g * 8);
    u16x8 o0, o1;
#pragma unroll
    for (int j = 0; j < 8; ++j) {
      o0[j] = f2b(__builtin_bit_cast(float, (u32)a0[j] << 16) * rs);
      o1[j] = f2b(__builtin_bit_cast(float, (u32)a1[j] << 16) * rs);
    }
    qf0 = __builtin_bit_cast(bf16x8, o0);
    qf1 = __builtin_bit_cast(bf16x8, o1);
  }

  float m = -3.0e38f, l = 0.0f;   // per-lane scalars (query q0+c)
  f32x4 acc[4] = {};              // acc[dt][r] = O^T[dt*16+g*4+r][q0+c]
  const int src0 = ((g & 1) << 5) + c;   // lane 2*(g&1)*16 + c
  const int src1 = src0 + 16;
  const bool hig = (g >> 1) != 0;

#define STAGE(buf_, kc_) do {                                         \
    const u16* kg0 = Kb + (size_t)((kc_) + sr) * 64 + sx;             \
    const u16* kg1 = Kb + (size_t)((kc_) + 32 + sr) * 64 + sx;        \
    const u16* vg0 = Vb + (size_t)sr * 2048 + (kc_) + sx;             \
    const u16* vg1 = Vb + (size_t)(32 + sr) * 2048 + (kc_) + sx;      \
    u16* kd = &Ks[buf_][w * 512];                                     \
    u16* vd = &Vs[buf_][w * 512];                                     \
    GLD_TO_LDS(kg0, kd);                                              \
    GLD_TO_LDS(kg1, kd + 2048);                                       \
    GLD_TO_LDS(vg0, vd);                                              \
    GLD_TO_LDS(vg1, vd + 2048);                                       \
  } while (0)

  STAGE(0, 0);

  for (int kc = 0; kc < 2048; kc += 64) {
    const int buf = (kc >> 6) & 1;
    if (kc + 64 < 2048) {
      STAGE(buf ^ 1, kc + 64);
      asm volatile("s_waitcnt vmcnt(4)" ::: "memory");  // current tile drained
    } else {
      asm volatile("s_waitcnt vmcnt(0)" ::: "memory");
    }
    __builtin_amdgcn_s_barrier();

    const u16* Kt = &Ks[buf][0];
    const u16* Vq = &Vs[buf][0];

    // S^T = mfma(K, Q): s[j][r] = S[key = j*16+g*4+r][q = q0+c]
    f32x4 s[4];
#pragma unroll
    for (int j = 0; j < 4; ++j) {
      const int rk = j * 16 + c;
      const bf16x8 k0 = *(const bf16x8*)(Kt + rk * 64 + ((((g << 4)) ^ swz) >> 1));
      const bf16x8 k1 = *(const bf16x8*)(Kt + rk * 64 + (((64 | (g << 4)) ^ swz) >> 1));
      const f32x4 z = {};
      __builtin_amdgcn_s_setprio(1);
      s[j] = __builtin_amdgcn_mfma_f32_16x16x32_bf16(k0, qf0, z, 0, 0, 0);
      s[j] = __builtin_amdgcn_mfma_f32_16x16x32_bf16(k1, qf1, s[j], 0, 0, 0);
      __builtin_amdgcn_s_setprio(0);
    }

    // V^T frags (b128, conflict-free): k-slot g*8+jj <-> key 32kk+8g+jj
    bf16x8 vf[4][2];
#pragma unroll
    for (int dt = 0; dt < 4; ++dt) {
      const int rv = dt * 16 + c;
#pragma unroll
      for (int kk = 0; kk < 2; ++kk)
        vf[dt][kk] = *(const bf16x8*)(Vq + rv * 64 + ((((kk << 6) | (g << 4)) ^ swz) >> 1));
    }

    // defer-max: per-lane max + one ballot; column tree only on rare growth
    float tl = s[0][0];
#pragma unroll
    for (int j = 0; j < 4; ++j)
#pragma unroll
      for (int r = 0; r < 4; ++r) tl = fmaxf(tl, s[j][r]);
    if (__any(tl > m + 8.0f)) {
      tl = fmaxf(tl, __shfl_xor(tl, 16));
      tl = fmaxf(tl, __shfl_xor(tl, 32));
      const float mn = fmaxf(m, tl);
      const float corr = __builtin_amdgcn_exp2f(m - mn);
      m = mn;
      l *= corr;
#pragma unroll
      for (int dt = 0; dt < 4; ++dt)
#pragma unroll
        for (int r = 0; r < 4; ++r) acc[dt][r] *= corr;
    }

    // P = exp2(s - m), lane-local l accum; pack to bf16x2 words
    float p[4][4];
#pragma unroll
    for (int j = 0; j < 4; ++j)
#pragma unroll
      for (int r = 0; r < 4; ++r) {
        p[j][r] = __builtin_amdgcn_exp2f(s[j][r] - m);
        l += p[j][r];
      }
    u32 W[4][2];
#pragma unroll
    for (int j = 0; j < 4; ++j)
#pragma unroll
      for (int rp = 0; rp < 2; ++rp) {
        bf16x2 t2;
        t2[0] = (__bf16)p[j][2 * rp];
        t2[1] = (__bf16)p[j][2 * rp + 1];
        W[j][rp] = __builtin_bit_cast(u32, t2);
      }
    // redistribute: dest lane (g,c) B-frag word w=2*gs+rp of chunk kk is
    // W[2kk+(g>>1)][rp] from lane (2*(g&1)+gs)*16+c
    u32 R[4][2][2];
#pragma unroll
    for (int q = 0; q < 4; ++q)
#pragma unroll
      for (int rp = 0; rp < 2; ++rp) {
        R[q][rp][0] = (u32)__shfl((int)W[q][rp], src0);
        R[q][rp][1] = (u32)__shfl((int)W[q][rp], src1);
      }
    u32x4 pw0, pw1;
#pragma unroll
    for (int gs = 0; gs < 2; ++gs)
#pragma unroll
      for (int rp = 0; rp < 2; ++rp) {
        pw0[gs * 2 + rp] = hig ? R[1][rp][gs] : R[0][rp][gs];
        pw1[gs * 2 + rp] = hig ? R[3][rp][gs] : R[2][rp][gs];
      }
    const bf16x8 pb0 = __builtin_bit_cast(bf16x8, pw0);
    const bf16x8 pb1 = __builtin_bit_cast(bf16x8, pw1);

    // PV (swapped): O^T[d][q] accum; A=V^T frag, B=P^T frag
    __builtin_amdgcn_s_setprio(1);
#pragma unroll
    for (int dt = 0; dt < 4; ++dt) {
      acc[dt] = __builtin_amdgcn_mfma_f32_16x16x32_bf16(vf[dt][0], pb0, acc[dt], 0, 0, 0);
      acc[dt] = __builtin_amdgcn_mfma_f32_16x16x32_bf16(vf[dt][1], pb1, acc[dt], 0, 0, 0);
    }
    __builtin_amdgcn_s_setprio(0);

    __builtin_amdgcn_s_barrier();   // reads of buf done before next overwrite
  }
#undef STAGE

  // column l: sum the 4 g-partials of each query column (once)
  l += __shfl_xor(l, 16);
  l += __shfl_xor(l, 32);
  const float inv = 1.0f / l;

#pragma unroll
  for (int dt = 0; dt < 4; ++dt)
#pragma unroll
    for (int r = 0; r < 4; ++r) {
      const int trow = q0 + c;
      const int dd = dt * 16 + g * 4 + r;
      // Oh layout [b][t][h][d] == flat [m][1024] for the output GEMM
      Oh[(((size_t)b * 2048 + trow) * 16 + h) * 64 + dd] = f2b(acc[dt][r] * inv);
    }
}

// ---------------- launch --------------------------------------------------
extern "C" void kernel_launch(void* const* d_in, const int* in_sizes, int n_in,
                              void* d_out, int out_size, void* d_ws, size_t ws_size,
                              hipStream_t stream) {
  const float* query = (const float*)d_in[0];
  const float* key_  = (const float*)d_in[1];
  const float* value = (const float*)d_in[2];
  const float* phi   = (const float*)d_in[3];
  // d_in[4] logvar: cancels in softmax (additive per-query bias)
  const float* Wq = (const float*)d_in[5];
  const float* bq = (const float*)d_in[6];
  const float* Wk = (const float*)d_in[7];
  const float* bk = (const float*)d_in[8];
  const float* Wv = (const float*)d_in[9];
  const float* bv = (const float*)d_in[10];
  const float* Wo = (const float*)d_in[11];
  const float* bo = (const float*)d_in[12];
  // d_in[13] w_sigma, d_in[14] w_phi: cancel in softmax

  char* ws = (char*)d_ws;
  const size_t MB = 1u << 20;
  u16* Xq  = (u16*)(ws);             // 8MB; reused as Oh after QKV GEMM
  u16* Xk  = (u16*)(ws + 8 * MB);    // 8MB
  u16* Xv  = (u16*)(ws + 16 * MB);   // 8MB
  u16* Wqb = (u16*)(ws + 24 * MB);   // 2MB each
  u16* Wkb = (u16*)(ws + 26 * MB);
  u16* Wvb = (u16*)(ws + 28 * MB);
  u16* Wob = (u16*)(ws + 30 * MB);
  u16* Qh  = (u16*)(ws + 32 * MB);   // 8MB each
  u16* Kh  = (u16*)(ws + 40 * MB);
  u16* Vt  = (u16*)(ws + 48 * MB);   // V^T written directly by QKV GEMM
  float* rscale = (float*)(ws + 56 * MB);  // 16KB
  u16* Oh = Xq;

  prep_kernel<<<16384, 256, 0, stream>>>(query, key_, value, Wq, Wk, Wv, Wo, phi,
                                         Xq, Xk, Xv, Wqb, Wkb, Wvb, Wob, rscale);
  gemm_qkv_kernel<<<dim3(8, 32, 3), 256, 0, stream>>>(Xq, Xk, Xv, Wqb, Wkb, Wvb,
                                                      bq, bk, bv, Qh, Kh, Vt);
  attn_kernel<<<dim3(32, 32), 256, 0, stream>>>(Qh, Kh, Vt, rscale, Oh);
  gemm_o_kernel<<<dim3(8, 32), 256, 0, stream>>>(Oh, Wob, bo, (float*)d_out);
}

// Round 10
// 257.937 us; speedup vs baseline: 1.1512x; 1.1512x over previous
//
#include <hip/hip_runtime.h>

// ud_MultiheadSoftmaxAttention: B=2 T=2048 D=1024 H=16 hd=64
// Pipeline: prep(fp32->bf16 + row scales) -> batched QKV GEMM (bf16 MFMA,
//           dbuf+counted vmcnt) -> V transpose (with bit3 half-swap pre-swizzle)
//           -> flash attention (LDS-staged K/V, swapped-operand in-register
//           softmax, shufflevector packing, conflict-fixed b64 V reads)
//           -> output GEMM.
// Per-query additive score biases (logvar/w_phi terms) cancel in softmax;
// only the per-row temperature 1/(8*max(mean(phi),1e-6)) survives.

typedef __bf16 bf16x8 __attribute__((ext_vector_type(8)));
typedef __bf16 bf16x4 __attribute__((ext_vector_type(4)));
typedef float f32x4 __attribute__((ext_vector_type(4)));
typedef unsigned short u16;
typedef unsigned int u32;
typedef u16 u16x8 __attribute__((ext_vector_type(8)));

#define GLD_TO_LDS(g, l) __builtin_amdgcn_global_load_lds( \
    (const __attribute__((address_space(1))) void*)(g),    \
    (__attribute__((address_space(3))) void*)(l), 16, 0, 0)

__device__ __forceinline__ u16 f2b(float f) {
  u32 u = __builtin_bit_cast(u32, f);
  u += 0x7fffu + ((u >> 16) & 1u);   // RNE
  return (u16)(u >> 16);
}

// ---------------- prep: fp32 -> bf16 conversions + softmax row scales ----
__global__ __launch_bounds__(256) void prep_kernel(
    const float* __restrict__ query, const float* __restrict__ key,
    const float* __restrict__ value, const float* __restrict__ Wq,
    const float* __restrict__ Wk, const float* __restrict__ Wv,
    const float* __restrict__ Wo, const float* __restrict__ phi,
    u16* __restrict__ Xq, u16* __restrict__ Xk, u16* __restrict__ Xv,
    u16* __restrict__ Wqb, u16* __restrict__ Wkb, u16* __restrict__ Wvb,
    u16* __restrict__ Wob, float* __restrict__ rscale)
{
  const long gid = (long)blockIdx.x * 256 + threadIdx.x;  // 0..4M-1
  const long e = gid * 4;
  const float* src; u16* dst; long off;
  if (e < 4194304L)       { src = query; dst = Xq;  off = e; }
  else if (e < 8388608L)  { src = key;   dst = Xk;  off = e - 4194304L; }
  else if (e < 12582912L) { src = value; dst = Xv;  off = e - 8388608L; }
  else if (e < 13631488L) { src = Wq;    dst = Wqb; off = e - 12582912L; }
  else if (e < 14680064L) { src = Wk;    dst = Wkb; off = e - 13631488L; }
  else if (e < 15728640L) { src = Wv;    dst = Wvb; off = e - 14680064L; }
  else                    { src = Wo;    dst = Wob; off = e - 15728640L; }
  const float4 v = *(const float4*)(src + off);
  ushort4 o;
  o.x = f2b(v.x); o.y = f2b(v.y); o.z = f2b(v.z); o.w = f2b(v.w);
  *(ushort4*)(dst + off) = o;

  if (gid < 4096) {  // per-token softmax temperature (log2e folded in)
    const float4 p0 = *(const float4*)(phi + gid * 8);
    const float4 p1 = *(const float4*)(phi + gid * 8 + 4);
    const float mean = (p0.x + p0.y + p0.z + p0.w + p1.x + p1.y + p1.z + p1.w) * 0.125f;
    rscale[gid] = 1.4426950408889634f / (8.0f * fmaxf(mean, 1e-6f));
  }
}

// ---------------- GEMM: C[m][n] = A[m][:] . Bw[n][:] + bias[n] -----------
// 128x128 tile, BK=32, 256 thr (4 waves 2x2), global_load_lds width-16,
// double-buffered LDS + counted vmcnt(4) + raw barriers (no full drain).
// MODE 0: bf16 out in per-head layout [b][h][t][64]; MODE 1: f32 flat out.
template<int MODE>
__device__ __forceinline__ void gemm_body(
    u16 (*As)[4096], u16 (*Bs)[4096], int m0, int n0,
    const u16* __restrict__ A, const u16* __restrict__ Bw,
    const float* __restrict__ bias, void* __restrict__ Cout)
{
  constexpr int K = 1024;
  const int t = threadIdx.x;
  const int lane = t & 63, w = t >> 6;
  const int g = lane >> 4, c = lane & 15;
  const int srow = t >> 2, skc = (t & 3) * 8;
  const u16* gA = A + (size_t)(m0 + srow) * K + skc;
  const u16* gB = Bw + (size_t)(n0 + srow) * K + skc;
  const int wm = (w >> 1) * 64, wn = (w & 1) * 64;

  f32x4 acc[4][4] = {};

#define STG(b_, k0_) do {                              \
    GLD_TO_LDS(gA + (k0_), &As[b_][w * 512]);          \
    GLD_TO_LDS(gA + 64 * K + (k0_), &As[b_][w * 512 + 2048]); \
    GLD_TO_LDS(gB + (k0_), &Bs[b_][w * 512]);          \
    GLD_TO_LDS(gB + 64 * K + (k0_), &Bs[b_][w * 512 + 2048]); \
  } while (0)

  STG(0, 0);
  for (int i = 0; i < 32; ++i) {
    const int buf = i & 1;
    if (i < 31) {
      STG(buf ^ 1, (i + 1) * 32);
      asm volatile("s_waitcnt vmcnt(4)" ::: "memory");  // current tile drained
    } else {
      asm volatile("s_waitcnt vmcnt(0)" ::: "memory");
    }
    __builtin_amdgcn_s_barrier();
    bf16x8 af[4], bfr[4];
#pragma unroll
    for (int mi = 0; mi < 4; ++mi)
      af[mi] = *(const bf16x8*)(&As[buf][0] + (wm + mi * 16 + c) * 32 + g * 8);
#pragma unroll
    for (int ni = 0; ni < 4; ++ni)
      bfr[ni] = *(const bf16x8*)(&Bs[buf][0] + (wn + ni * 16 + c) * 32 + g * 8);
#pragma unroll
    for (int mi = 0; mi < 4; ++mi)
#pragma unroll
      for (int ni = 0; ni < 4; ++ni)
        acc[mi][ni] = __builtin_amdgcn_mfma_f32_16x16x32_bf16(
            af[mi], bfr[ni], acc[mi][ni], 0, 0, 0);
    __builtin_amdgcn_s_barrier();  // reads done before next overwrite
  }
#undef STG

#pragma unroll
  for (int ni = 0; ni < 4; ++ni) {
    const int ncol = n0 + wn + ni * 16 + c;
    const float bv = bias[ncol];
#pragma unroll
    for (int mi = 0; mi < 4; ++mi) {
#pragma unroll
      for (int r = 0; r < 4; ++r) {
        const int mrow = m0 + wm + mi * 16 + g * 4 + r;  // C/D: col=lane&15, row=(lane>>4)*4+r
        const float val = acc[mi][ni][r] + bv;
        if (MODE == 0) {
          const int bb = mrow >> 11, tt = mrow & 2047;
          const int hh = ncol >> 6, dd = ncol & 63;
          ((u16*)Cout)[((((size_t)bb * 16 + hh) * 2048 + tt) << 6) + dd] = f2b(val);
        } else {
          ((float*)Cout)[(size_t)mrow * 1024 + ncol] = val;
        }
      }
    }
  }
}

__global__ __launch_bounds__(256) void gemm_qkv_kernel(
    const u16* __restrict__ Xq, const u16* __restrict__ Xk, const u16* __restrict__ Xv,
    const u16* __restrict__ Wqb, const u16* __restrict__ Wkb, const u16* __restrict__ Wvb,
    const float* __restrict__ bq, const float* __restrict__ bk, const float* __restrict__ bv,
    u16* __restrict__ Qh, u16* __restrict__ Kh, u16* __restrict__ Vh)
{
  __shared__ __align__(16) u16 As[2][4096], Bs[2][4096];
  // bijective chunked XCD remap: 768 blocks = 8 chunks x 96 -> x-siblings
  // (sharing a 256KB A-panel) stay on one XCD's L2.
  const u32 n = blockIdx.z * 256u + blockIdx.y * 8u + blockIdx.x;
  const u32 nl = (n & 7u) * 96u + (n >> 3);
  const int bx = nl & 7, by = (nl >> 3) & 31, bz = nl >> 8;
  const u16* A = (bz == 0) ? Xq : (bz == 1) ? Xk : Xv;
  const u16* W = (bz == 0) ? Wqb : (bz == 1) ? Wkb : Wvb;
  const float* bias = (bz == 0) ? bq : (bz == 1) ? bk : bv;
  u16* C = (bz == 0) ? Qh : (bz == 1) ? Kh : Vh;
  gemm_body<0>(As, Bs, by * 128, bx * 128, A, W, bias, C);
}

__global__ __launch_bounds__(256) void gemm_o_kernel(
    const u16* __restrict__ Oh, const u16* __restrict__ Wob,
    const float* __restrict__ bo, float* __restrict__ out)
{
  __shared__ __align__(16) u16 As[2][4096], Bs[2][4096];
  const u32 n = blockIdx.y * 8u + blockIdx.x;
  const u32 nl = (n & 7u) * 32u + (n >> 3);
  gemm_body<1>(As, Bs, (int)(nl >> 3) * 128, (int)(nl & 7) * 128, Oh, Wob, bo, out);
}

// ---------------- V transpose: [bh][t][64] -> [bh][64][t] ----------------
// Writes V^T with a 4-u16 half-swap on rows with d&8 (bit3 of the attn
// LDS bank swizzle, pre-applied in global data so global_load_lds stays
// linear-dest; attn read addr XORs it back).
__global__ __launch_bounds__(256) void transpose_v_kernel(
    const u16* __restrict__ Vh, u16* __restrict__ Vt)
{
  __shared__ __align__(16) u16 tile[64][72];
  const int bh = blockIdx.y, t0 = blockIdx.x * 64;
  const int tid = threadIdx.x;
  const int r = tid >> 3, cc = (tid & 7) * 8;
  const u16* src = Vh + ((size_t)bh * 2048 + t0) * 64;
#pragma unroll
  for (int it = 0; it < 2; ++it)
    *(u16x8*)&tile[r + 32 * it][cc] = *(const u16x8*)(src + (size_t)(r + 32 * it) * 64 + cc);
  __syncthreads();
  u16* dst = Vt + (size_t)bh * 64 * 2048 + t0;
  const int sw = (r & 8) ? 4 : 0;   // half-swap within each 8-u16 chunk
#pragma unroll
  for (int it = 0; it < 2; ++it) {
    const int d = r + 32 * it;       // d&8 == r&8
    u16x8 v;
#pragma unroll
    for (int j = 0; j < 8; ++j) v[j] = tile[cc + (j ^ sw)][d];
    *(u16x8*)(dst + (size_t)d * 2048 + cc) = v;
  }
}

// ---------------- flash attention ----------------------------------------
// grid 1024 blocks (XCD-swizzled), 256 thr = 4 waves, 16 q-rows each, KB=64.
// K/V staged in LDS (dbuf, counted vmcnt(4)). Swapped QK^T: S^T = mfma(K,Q),
// lane owns query col c -> softmax fully in-register (defer-max THR=8,
// lane-local l). P stays lane-resident: key permutation kappa(g*8+jj) =
// (jj>>2)*16 + g*4 + (jj&3) applied to BOTH PV operands; V^T b64 reads use
// the bit3-extended swizzle (mask ((rv&7)<<4)|(rv&8)) -> 2-way max.
// All fragment packing via shufflevector (register concat, no elem inserts).
__global__ __launch_bounds__(256) void attn_kernel(
    const u16* __restrict__ Qh, const u16* __restrict__ Kh,
    const u16* __restrict__ Vt, const float* __restrict__ rscale,
    u16* __restrict__ Oh)
{
  __shared__ __align__(16) u16 Ks[2][4096];  // [buf][64 keys][64 d], swizzled
  __shared__ __align__(16) u16 Vs[2][4096];  // [buf][64 d][64 keys], swizzled

  // bijective XCD remap: group consecutive bh per XCD so K/V stay L2-resident
  const u32 orig = blockIdx.y * 32 + blockIdx.x;   // HW dispatch-linear id
  const u32 newL = (orig & 7u) * 128u + (orig >> 3);
  const int qx = newL & 31, bh = newL >> 5;
  const int b = bh >> 4, h = bh & 15;

  const int t = threadIdx.x;
  const int w = t >> 6, lane = t & 63;
  const int g = lane >> 4, c = lane & 15;
  const int q0 = qx * 64 + w * 16;
  const int swz = (c & 7) << 4;          // K-read XOR swizzle (rows == c mod 8)

  const u16* Qb = Qh + (size_t)bh * (2048 * 64);
  const u16* Kb = Kh + (size_t)bh * (2048 * 64);
  const u16* Vb = Vt + (size_t)bh * (64 * 2048);

  // staging geometry: 256 thr x 16B = 4KB/instr = 32 rows x 128B
  const int sr = t >> 3;                       // row 0..31
  const int sx = ((t & 7) ^ (sr & 7)) * 8;     // inverse-swizzled u16 col

  // Q fragment (B-operand: col=q=c, k=d) with per-row temperature folded in
  const float rs = rscale[b * 2048 + q0 + c];
  bf16x8 qf0, qf1;
  {
    const u16x8 a0 = *(const u16x8*)(Qb + (size_t)(q0 + c) * 64 + g * 8);
    const u16x8 a1 = *(const u16x8*)(Qb + (size_t)(q0 + c) * 64 + 32 + g * 8);
    u16x8 o0, o1;
#pragma unroll
    for (int j = 0; j < 8; ++j) {
      o0[j] = f2b(__builtin_bit_cast(float, (u32)a0[j] << 16) * rs);
      o1[j] = f2b(__builtin_bit_cast(float, (u32)a1[j] << 16) * rs);
    }
    qf0 = __builtin_bit_cast(bf16x8, o0);
    qf1 = __builtin_bit_cast(bf16x8, o1);
  }

  float m = -3.0e38f, l = 0.0f;   // per-lane scalars (query q0+c)
  f32x4 acc[4] = {};              // acc[dt][r] = O^T[dt*16+g*4+r][q0+c]

#define STAGE(buf_, kc_) do {                                         \
    const u16* kg0 = Kb + (size_t)((kc_) + sr) * 64 + sx;             \
    const u16* kg1 = Kb + (size_t)((kc_) + 32 + sr) * 64 + sx;        \
    const u16* vg0 = Vb + (size_t)sr * 2048 + (kc_) + sx;             \
    const u16* vg1 = Vb + (size_t)(32 + sr) * 2048 + (kc_) + sx;      \
    u16* kd = &Ks[buf_][w * 512];                                     \
    u16* vd = &Vs[buf_][w * 512];                                     \
    GLD_TO_LDS(kg0, kd);                                              \
    GLD_TO_LDS(kg1, kd + 2048);                                       \
    GLD_TO_LDS(vg0, vd);                                              \
    GLD_TO_LDS(vg1, vd + 2048);                                       \
  } while (0)

  STAGE(0, 0);

  for (int kc = 0; kc < 2048; kc += 64) {
    const int buf = (kc >> 6) & 1;
    if (kc + 64 < 2048) {
      STAGE(buf ^ 1, kc + 64);
      asm volatile("s_waitcnt vmcnt(4)" ::: "memory");  // current tile drained
    } else {
      asm volatile("s_waitcnt vmcnt(0)" ::: "memory");
    }
    __builtin_amdgcn_s_barrier();

    const u16* Kt = &Ks[buf][0];
    const u16* Vq = &Vs[buf][0];

    // S^T = mfma(K, Q): s[j][r] = S[key = j*16+g*4+r][q = q0+c]
    f32x4 s[4];
#pragma unroll
    for (int j = 0; j < 4; ++j) {
      const int rk = j * 16 + c;
      const bf16x8 k0 = *(const bf16x8*)(Kt + rk * 64 + ((((g << 4)) ^ swz) >> 1));
      const bf16x8 k1 = *(const bf16x8*)(Kt + rk * 64 + (((64 | (g << 4)) ^ swz) >> 1));
      const f32x4 z = {};
      __builtin_amdgcn_s_setprio(1);
      s[j] = __builtin_amdgcn_mfma_f32_16x16x32_bf16(k0, qf0, z, 0, 0, 0);
      s[j] = __builtin_amdgcn_mfma_f32_16x16x32_bf16(k1, qf1, s[j], 0, 0, 0);
      __builtin_amdgcn_s_setprio(0);
    }

    // V^T A-frags (kappa layout): per dt, 4x b64 at keys 4g + {0,16,32,48},
    // swizzle mask incl bit3 (matches transpose_v pre-swap) -> 2-way max.
    bf16x8 va[4][2];
#pragma unroll
    for (int dt = 0; dt < 4; ++dt) {
      const int rv = dt * 16 + c;
      const u16* vrow = Vq + rv * 64;
      const int xr = ((rv & 7) << 4) | (rv & 8);
      const bf16x4 a0 = *(const bf16x4*)(vrow + (((g * 8) ^ xr) >> 1));
      const bf16x4 a1 = *(const bf16x4*)(vrow + (((32 + g * 8) ^ xr) >> 1));
      const bf16x4 a2 = *(const bf16x4*)(vrow + (((64 + g * 8) ^ xr) >> 1));
      const bf16x4 a3 = *(const bf16x4*)(vrow + (((96 + g * 8) ^ xr) >> 1));
      va[dt][0] = __builtin_shufflevector(a0, a1, 0, 1, 2, 3, 4, 5, 6, 7);
      va[dt][1] = __builtin_shufflevector(a2, a3, 0, 1, 2, 3, 4, 5, 6, 7);
    }

    // defer-max: per-lane max + one ballot; column tree only on rare growth
    float tl = s[0][0];
#pragma unroll
    for (int j = 0; j < 4; ++j)
#pragma unroll
      for (int r = 0; r < 4; ++r) tl = fmaxf(tl, s[j][r]);
    if (__any(tl > m + 8.0f)) {
      tl = fmaxf(tl, __shfl_xor(tl, 16));
      tl = fmaxf(tl, __shfl_xor(tl, 32));
      const float mn = fmaxf(m, tl);
      const float corr = __builtin_amdgcn_exp2f(m - mn);
      m = mn;
      l *= corr;
#pragma unroll
      for (int dt = 0; dt < 4; ++dt)
#pragma unroll
        for (int r = 0; r < 4; ++r) acc[dt][r] *= corr;
    }

    // P = exp2(s - m): vector exp, lane-local l, shufflevector concat packs
    f32x4 pv[4];
#pragma unroll
    for (int j = 0; j < 4; ++j)
#pragma unroll
      for (int r = 0; r < 4; ++r) pv[j][r] = __builtin_amdgcn_exp2f(s[j][r] - m);
#pragma unroll
    for (int j = 0; j < 4; ++j)
      l += pv[j][0] + pv[j][1] + pv[j][2] + pv[j][3];
    bf16x4 pc[4];
#pragma unroll
    for (int j = 0; j < 4; ++j) {
      pc[j][0] = (__bf16)pv[j][0];
      pc[j][1] = (__bf16)pv[j][1];
      pc[j][2] = (__bf16)pv[j][2];
      pc[j][3] = (__bf16)pv[j][3];
    }
    const bf16x8 pb0 = __builtin_shufflevector(pc[0], pc[1], 0, 1, 2, 3, 4, 5, 6, 7);
    const bf16x8 pb1 = __builtin_shufflevector(pc[2], pc[3], 0, 1, 2, 3, 4, 5, 6, 7);

    // PV (swapped): O^T[d][q] accum; A=V^T kappa-frag, B=P^T kappa-frag
    __builtin_amdgcn_s_setprio(1);
#pragma unroll
    for (int dt = 0; dt < 4; ++dt) {
      acc[dt] = __builtin_amdgcn_mfma_f32_16x16x32_bf16(va[dt][0], pb0, acc[dt], 0, 0, 0);
      acc[dt] = __builtin_amdgcn_mfma_f32_16x16x32_bf16(va[dt][1], pb1, acc[dt], 0, 0, 0);
    }
    __builtin_amdgcn_s_setprio(0);

    __builtin_amdgcn_s_barrier();   // reads of buf done before next overwrite
  }
#undef STAGE

  // column l: sum the 4 g-partials of each query column (once)
  l += __shfl_xor(l, 16);
  l += __shfl_xor(l, 32);
  const float inv = 1.0f / l;

#pragma unroll
  for (int dt = 0; dt < 4; ++dt)
#pragma unroll
    for (int r = 0; r < 4; ++r) {
      const int trow = q0 + c;
      const int dd = dt * 16 + g * 4 + r;
      // Oh layout [b][t][h][d] == flat [m][1024] for the output GEMM
      Oh[(((size_t)b * 2048 + trow) * 16 + h) * 64 + dd] = f2b(acc[dt][r] * inv);
    }
}

// ---------------- launch --------------------------------------------------
extern "C" void kernel_launch(void* const* d_in, const int* in_sizes, int n_in,
                              void* d_out, int out_size, void* d_ws, size_t ws_size,
                              hipStream_t stream) {
  const float* query = (const float*)d_in[0];
  const float* key_  = (const float*)d_in[1];
  const float* value = (const float*)d_in[2];
  const float* phi   = (const float*)d_in[3];
  // d_in[4] logvar: cancels in softmax (additive per-query bias)
  const float* Wq = (const float*)d_in[5];
  const float* bq = (const float*)d_in[6];
  const float* Wk = (const float*)d_in[7];
  const float* bk = (const float*)d_in[8];
  const float* Wv = (const float*)d_in[9];
  const float* bv = (const float*)d_in[10];
  const float* Wo = (const float*)d_in[11];
  const float* bo = (const float*)d_in[12];
  // d_in[13] w_sigma, d_in[14] w_phi: cancel in softmax

  char* ws = (char*)d_ws;
  const size_t MB = 1u << 20;
  u16* Xq  = (u16*)(ws);             // 8MB; reused as Oh after QKV GEMM
  u16* Xk  = (u16*)(ws + 8 * MB);    // 8MB; reused as Vt after QKV GEMM
  u16* Xv  = (u16*)(ws + 16 * MB);   // 8MB
  u16* Wqb = (u16*)(ws + 24 * MB);   // 2MB each
  u16* Wkb = (u16*)(ws + 26 * MB);
  u16* Wvb = (u16*)(ws + 28 * MB);
  u16* Wob = (u16*)(ws + 30 * MB);
  u16* Qh  = (u16*)(ws + 32 * MB);   // 8MB each
  u16* Kh  = (u16*)(ws + 40 * MB);
  u16* Vh  = (u16*)(ws + 48 * MB);
  float* rscale = (float*)(ws + 56 * MB);  // 16KB
  u16* Oh = Xq;
  u16* Vt = Xk;

  prep_kernel<<<16384, 256, 0, stream>>>(query, key_, value, Wq, Wk, Wv, Wo, phi,
                                         Xq, Xk, Xv, Wqb, Wkb, Wvb, Wob, rscale);
  gemm_qkv_kernel<<<dim3(8, 32, 3), 256, 0, stream>>>(Xq, Xk, Xv, Wqb, Wkb, Wvb,
                                                      bq, bk, bv, Qh, Kh, Vh);
  transpose_v_kernel<<<dim3(32, 32), 256, 0, stream>>>(Vh, Vt);
  attn_kernel<<<dim3(32, 32), 256, 0, stream>>>(Qh, Kh, Vt, rscale, Oh);
  gemm_o_kernel<<<dim3(8, 32), 256, 0, stream>>>(Oh, Wob, bo, (float*)d_out);
}